// Round 24
// baseline (91.307 us; speedup 1.0000x reference)
//
#include <hip/hip_runtime.h>
#include <hip/hip_bf16.h>

typedef __bf16 v8bf __attribute__((ext_vector_type(8)));
typedef float f32x4 __attribute__((ext_vector_type(4)));
typedef float f32x16 __attribute__((ext_vector_type(16)));
typedef int v2i __attribute__((ext_vector_type(2)));
typedef int v4i __attribute__((ext_vector_type(4)));

#define MFMA16(a, b, c) __builtin_amdgcn_mfma_f32_16x16x32_bf16(a, b, c, 0, 0, 0)
#define MFMA32(a, b, c) __builtin_amdgcn_mfma_f32_32x32x16_bf16(a, b, c, 0, 0, 0)
#define GLOAD16(gp, lp)                                                        \
  __builtin_amdgcn_global_load_lds(                                            \
      (const __attribute__((address_space(1))) void*)(gp),                     \
      (__attribute__((address_space(3))) void*)(lp), 16, 0, 0)

// q scale = SCALE * log2(e) so that exp2(qk) == exp(qk*SCALE)
#define QSCALE 0.18033688011112042f

// ---------------- K0: weights -> MFMA-fragment-ordered bf16 ----------------
__global__ __launch_bounds__(256) void k_cvt_w(const float* __restrict__ qw,
                                               const float* __restrict__ kw,
                                               const float* __restrict__ vw,
                                               const float* __restrict__ ow,
                                               __bf16* __restrict__ wfrag,
                                               __bf16* __restrict__ owfrag) {
  int t = blockIdx.x * 256 + threadIdx.x;  // 640*256 = 163840
  if (t < 98304) {
    int e = t & 7, idx = t >> 3;
    int l = idx & 63; idx >>= 6;
    int n = idx & 3; idx >>= 2;
    int kk = idx & 7, nb = idx >> 3;
    int nn = nb * 64 + n * 16 + (l & 15);
    int k = kk * 32 + 8 * (l >> 4) + e;
    float v;
    if (nn < 256) v = qw[k * 256 + nn] * QSCALE;
    else if (nn < 320) v = kw[k * 64 + (nn - 256)];
    else v = vw[k * 64 + (nn - 320)];
    wfrag[t] = (__bf16)v;
  } else {
    int u = t - 98304;
    int e = u & 7, idx = u >> 3;
    int l = idx & 63; idx >>= 6;
    int n = idx & 3; idx >>= 2;
    int kk = idx & 7, nb = idx >> 3;
    int nn = nb * 64 + n * 16 + (l & 15);
    int k = kk * 32 + 8 * (l >> 4) + e;
    owfrag[u] = (__bf16)ow[k * 256 + nn];
  }
}

// ---------------- K1: fused QKV projection GEMM, BM=16, grid 2048 ----------
// Each block owns 16 rows; wave w handles col-fragments cf = 6w..6w+5
// (cols 96w..96w+95). Per-output FP chain identical to before (same
// kk-ascending MFMA over the same fragments).
__global__ __launch_bounds__(256) void k_qkv(const float* __restrict__ x,
                                             const __bf16* __restrict__ wfrag,
                                             const float* __restrict__ qb,
                                             const float* __restrict__ kb,
                                             const float* __restrict__ vb,
                                             __bf16* __restrict__ qo,
                                             __bf16* __restrict__ klin,
                                             __bf16* __restrict__ vlin) {
  int bx = blockIdx.x;
  int mb = (bx & 7) * 256 + (bx >> 3);  // 2048 % 8 == 0: bijective XCD chunk
  int wave = threadIdx.x >> 6, lane = threadIdx.x & 63;
  int g = lane >> 4, c = lane & 15;
  int r0 = mb * 16;
  const v8bf* wf = (const v8bf*)wfrag;

  v8bf a[8];
#pragma unroll
  for (int kk = 0; kk < 8; ++kk) {
    const float* ap = x + (size_t)(r0 + c) * 256 + kk * 32 + 8 * g;
    float4 f0 = *(const float4*)ap;
    float4 f1 = *(const float4*)(ap + 4);
    v8bf t;
    t[0] = (__bf16)f0.x; t[1] = (__bf16)f0.y; t[2] = (__bf16)f0.z; t[3] = (__bf16)f0.w;
    t[4] = (__bf16)f1.x; t[5] = (__bf16)f1.y; t[6] = (__bf16)f1.z; t[7] = (__bf16)f1.w;
    a[kk] = t;
  }
  f32x4 acc[6];
#pragma unroll
  for (int i = 0; i < 6; ++i) acc[i] = f32x4{0.f, 0.f, 0.f, 0.f};
#pragma unroll
  for (int kk = 0; kk < 8; ++kk) {
    v8bf bf[6];
#pragma unroll
    for (int i = 0; i < 6; ++i) {
      int cf = wave * 6 + i;  // cf = nb*4 + n
      bf[i] = wf[((((cf >> 2) * 8 + kk) * 4 + (cf & 3)) << 6) | lane];
    }
#pragma unroll
    for (int i = 0; i < 6; ++i) acc[i] = MFMA16(a[kk], bf[i], acc[i]);
  }
#pragma unroll
  for (int i = 0; i < 6; ++i) {
    int col = (wave * 6 + i) * 16 + c;
    float bias;
    if (col < 256) bias = qb[col] * QSCALE;
    else if (col < 320) bias = kb[col - 256];
    else bias = vb[col - 320];
#pragma unroll
    for (int j = 0; j < 4; ++j) {
      int row = r0 + 4 * g + j;
      float v = acc[i][j] + bias;
      if (col < 256) qo[(size_t)row * 256 + col] = (__bf16)v;
      else if (col < 320) klin[(size_t)row * 64 + (col - 256)] = (__bf16)v;
      else vlin[(size_t)row * 64 + (col - 320)] = (__bf16)v;
    }
  }
}

// ---------------- K2: depthwise conv -> staging-linear, e-split, grid 1024 -
// bx<512: K phase (e-half split), bx>=512: V phase (e-half split). The
// e-split mapping ran bit-identical inside R22's fused kernel.
__global__ __launch_bounds__(256) void k_conv(const __bf16* __restrict__ klin,
                                              const __bf16* __restrict__ vlin,
                                              const float* __restrict__ kw,
                                              const float* __restrict__ kbias,
                                              const float* __restrict__ vw,
                                              const float* __restrict__ vbias,
                                              __bf16* __restrict__ kcS,
                                              __bf16* __restrict__ vcS) {
  int bx = blockIdx.x;
  int phase = bx >> 9;             // 0: K, 1: V
  int sub = bx & 511;
  int half = sub >> 8;             // element half: e 0..3 / 4..7
  int b = (sub >> 5) & 7, tile = sub & 31;
  int u = threadIdx.x;

  if (phase == 0) {
    const __bf16* kin = klin + (size_t)b * 262144;
    int kj = u >> 5, kr = (u & 31) ^ kj;
    float acc[4];
#pragma unroll
    for (int e = 0; e < 4; ++e) acc[e] = kbias[kj * 8 + half * 4 + e];
#pragma unroll
    for (int dy = 0; dy < 3; ++dy) {
      int iy = 2 * tile - 1 + dy;
      if (iy < 0 || iy > 63) continue;
#pragma unroll
      for (int dx = 0; dx < 3; ++dx) {
        int ix = 2 * kr - 1 + dx;
        if (ix < 0 || ix > 63) continue;
        v8bf kv8 = *(const v8bf*)(kin + ((size_t)iy * 64 + ix) * 64 + kj * 8);
        const float* wp = kw + (dy * 3 + dx) * 64 + kj * 8 + half * 4;
#pragma unroll
        for (int e = 0; e < 4; ++e) acc[e] += (float)kv8[half * 4 + e] * wp[e];
      }
    }
    __bf16 o[4];
#pragma unroll
    for (int e = 0; e < 4; ++e) o[e] = (__bf16)acc[e];
    *(v2i*)(kcS + ((size_t)b * 32 + tile) * 2048 + u * 8 + half * 4) = *(v2i*)o;
  } else {
    const __bf16* vin = vlin + (size_t)b * 262144;
    int dt = u >> 7, ks = (u >> 6) & 1, vh = (u >> 5) & 1;
    int cc = (u & 31) ^ (ks * 2 + vh);
    int ch = dt * 32 + cc;
    float vwv[9];
#pragma unroll
    for (int i = 0; i < 9; ++i) vwv[i] = vw[i * 64 + ch];
    float vb0 = vbias[ch];
    __bf16 o[4];
#pragma unroll
    for (int e = 0; e < 4; ++e) {
      int ox = ks * 16 + vh * 8 + half * 4 + e;
      float av = vb0;
#pragma unroll
      for (int dy = 0; dy < 3; ++dy) {
        int iy = 2 * tile - 1 + dy;
        if (iy < 0 || iy > 63) continue;
#pragma unroll
        for (int dx = 0; dx < 3; ++dx) {
          int ix = 2 * ox - 1 + dx;
          if (ix < 0 || ix > 63) continue;
          av += (float)vin[((size_t)iy * 64 + ix) * 64 + ch] * vwv[dy * 3 + dx];
        }
      }
      o[e] = (__bf16)av;
    }
    *(v2i*)(vcS + ((size_t)b * 32 + tile) * 2048 + u * 8 + half * 4) = *(v2i*)o;
  }
}

// ---------------- K3: MQA flash attention + fused out-projection (R19) ----
__global__ __launch_bounds__(512, 4) void k_attn(const __bf16* __restrict__ q,
                                                 const __bf16* __restrict__ kcS,
                                                 const __bf16* __restrict__ vcS,
                                                 const __bf16* __restrict__ owfrag,
                                                 const float* __restrict__ ob,
                                                 float* __restrict__ out) {
  __shared__ __bf16 SMEM[16896];  // 3x4096 KV ring (24KB) / Ot[64][264] union
  int bx = blockIdx.x;
  int L = (bx & 7) * 64 + (bx >> 3);  // 512 % 8 == 0: bijective XCD chunk
  int b = L >> 6, qt = L & 63;
  int tid = threadIdx.x;
  int wave = tid >> 6, lane = tid & 63;
  int h = wave & 3, rg = wave >> 2;    // head / row-group
  int c = lane & 31, hi = lane >> 5;
  size_t rowBase = (size_t)b * 4096 + qt * 64;

  const __bf16* gsrc = (tid < 256)
                           ? kcS + (size_t)b * 65536 + tid * 8
                           : vcS + (size_t)b * 65536 + (tid - 256) * 8;
  __bf16* ldst = (tid < 256) ? &SMEM[tid * 8] : &SMEM[2048 + (tid - 256) * 8];

  int Koff[4], Voff[2][2];
#pragma unroll
  for (int kk = 0; kk < 4; ++kk) {
    int j = kk * 2 + hi;
    Koff[kk] = (j * 32 + (c ^ j)) * 8;
  }
#pragma unroll
  for (int ks = 0; ks < 2; ++ks)
#pragma unroll
    for (int dt = 0; dt < 2; ++dt) {
      int j = ks * 2 + hi;
      Voff[ks][dt] = (256 + dt * 128 + ks * 64 + hi * 32 + (c ^ j)) * 8;
    }

  const __bf16* qbase = q + (rowBase + rg * 32 + c) * 256 + h * 64 + hi * 8;
  v8bf Qf[4];
#pragma unroll
  for (int kk = 0; kk < 4; ++kk) Qf[kk] = *(const v8bf*)(qbase + kk * 16);

  f32x16 O0 = {}, O1 = {};
  const f32x16 Z16 = {};
  float ls0 = 0.f, ls1 = 0.f, ls2 = 0.f, ls3 = 0.f;

  GLOAD16(gsrc, ldst);
  GLOAD16(gsrc + 2048, ldst + 4096);

  int cur = 0;
  int nxt2 = 2;
  for (int it = 0; it < 32; ++it) {
    if (it < 31) {
      asm volatile("s_waitcnt vmcnt(1)" ::: "memory");
    } else {
      asm volatile("s_waitcnt vmcnt(0)" ::: "memory");
    }
    __builtin_amdgcn_sched_barrier(0);
    __builtin_amdgcn_s_barrier();
    __builtin_amdgcn_sched_barrier(0);
    if (it < 30) {
      GLOAD16(gsrc + (it + 2) * 2048, ldst + nxt2 * 4096);
    }

    const __bf16* base = &SMEM[cur * 4096];
    v8bf Kf[4], Vf[2][2];
#pragma unroll
    for (int kk = 0; kk < 4; ++kk) Kf[kk] = *(const v8bf*)(base + Koff[kk]);
#pragma unroll
    for (int ks = 0; ks < 2; ++ks)
#pragma unroll
      for (int dt = 0; dt < 2; ++dt)
        Vf[ks][dt] = *(const v8bf*)(base + Voff[ks][dt]);

    f32x16 S = MFMA32(Kf[0], Qf[0], Z16);
    S = MFMA32(Kf[1], Qf[1], S);
    S = MFMA32(Kf[2], Qf[2], S);
    S = MFMA32(Kf[3], Qf[3], S);

#pragma unroll
    for (int r = 0; r < 16; ++r) S[r] = __builtin_amdgcn_exp2f(S[r]);
    ls0 += (S[0] + S[1]) + (S[2] + S[3]);
    ls1 += (S[4] + S[5]) + (S[6] + S[7]);
    ls2 += (S[8] + S[9]) + (S[10] + S[11]);
    ls3 += (S[12] + S[13]) + (S[14] + S[15]);

    int w[8];
#pragma unroll
    for (int q2 = 0; q2 < 8; ++q2) {
      int r;
      asm("v_cvt_pk_bf16_f32 %0, %1, %2"
          : "=v"(r) : "v"(S[2 * q2]), "v"(S[2 * q2 + 1]));
      w[q2] = r;
    }
    v2i s1 = __builtin_amdgcn_permlane32_swap(w[2], w[0], false, false);
    v2i s2 = __builtin_amdgcn_permlane32_swap(w[3], w[1], false, false);
    v2i s3 = __builtin_amdgcn_permlane32_swap(w[6], w[4], false, false);
    v2i s4 = __builtin_amdgcn_permlane32_swap(w[7], w[5], false, false);
    v4i pa0i, pa1i;
    pa0i[0] = s1[1]; pa0i[1] = s2[1]; pa0i[2] = s1[0]; pa0i[3] = s2[0];
    pa1i[0] = s3[1]; pa1i[1] = s4[1]; pa1i[2] = s3[0]; pa1i[3] = s4[0];
    v8bf pa0 = *(v8bf*)&pa0i, pa1 = *(v8bf*)&pa1i;

    O0 = MFMA32(pa0, Vf[0][0], O0);
    O1 = MFMA32(pa0, Vf[0][1], O1);
    O0 = MFMA32(pa1, Vf[1][0], O0);
    O1 = MFMA32(pa1, Vf[1][1], O1);

    cur = (cur == 2) ? 0 : cur + 1;
    nxt2 = (nxt2 == 2) ? 0 : nxt2 + 1;
  }

  float lsum = (ls0 + ls1) + (ls2 + ls3);
  float tot = lsum + __shfl_xor(lsum, 32);
  float linv = 1.0f / tot;  // lane c holds 1/l for q-row rg*32+c

  __syncthreads();  // all waves done reading KV -> union region free

  __bf16(*Ot)[264] = (__bf16(*)[264])SMEM;
#pragma unroll
  for (int r = 0; r < 16; ++r) {
    int qr = (r & 3) + 8 * (r >> 2) + 4 * hi;
    float li = __shfl(linv, qr);
    Ot[rg * 32 + qr][h * 64 + c] = (__bf16)(O0[r] * li);
    Ot[rg * 32 + qr][h * 64 + 32 + c] = (__bf16)(O1[r] * li);
  }
  __syncthreads();

  int g = lane >> 4, c16 = lane & 15;
  const v8bf* wf = (const v8bf*)owfrag;
  f32x4 acc[2][4];
#pragma unroll
  for (int m = 0; m < 2; ++m)
#pragma unroll
    for (int n = 0; n < 4; ++n) acc[m][n] = f32x4{0.f, 0.f, 0.f, 0.f};
#pragma unroll
  for (int kk = 0; kk < 8; ++kk) {
    v8bf a0 = *(const v8bf*)&Ot[rg * 32 + c16][kk * 32 + 8 * g];
    v8bf a1 = *(const v8bf*)&Ot[rg * 32 + 16 + c16][kk * 32 + 8 * g];
    v8bf bf[4];
#pragma unroll
    for (int n = 0; n < 4; ++n)
      bf[n] = wf[(((h * 8 + kk) * 4 + n) << 6) | lane];
#pragma unroll
    for (int n = 0; n < 4; ++n) {
      acc[0][n] = MFMA16(a0, bf[n], acc[0][n]);
      acc[1][n] = MFMA16(a1, bf[n], acc[1][n]);
    }
  }
#pragma unroll
  for (int n = 0; n < 4; ++n) {
    int col = h * 64 + n * 16 + c16;
    float bias = ob[col];
#pragma unroll
    for (int m = 0; m < 2; ++m)
#pragma unroll
      for (int j = 0; j < 4; ++j) {
        int row = rg * 32 + m * 16 + 4 * g + j;
        out[(rowBase + row) * 256 + col] = acc[m][n][j] + bias;
      }
  }
}

// ---------------- launcher ----------------
extern "C" void kernel_launch(void* const* d_in, const int* in_sizes, int n_in,
                              void* d_out, int out_size, void* d_ws, size_t ws_size,
                              hipStream_t stream) {
  const float* x   = (const float*)d_in[0];
  const float* qw  = (const float*)d_in[1];
  const float* qb  = (const float*)d_in[2];
  const float* kw  = (const float*)d_in[3];
  const float* kb  = (const float*)d_in[4];
  const float* vw  = (const float*)d_in[5];
  const float* vb  = (const float*)d_in[6];
  const float* kcw = (const float*)d_in[7];
  const float* kcb = (const float*)d_in[8];
  const float* vcw = (const float*)d_in[9];
  const float* vcb = (const float*)d_in[10];
  const float* ow  = (const float*)d_in[11];
  const float* ob  = (const float*)d_in[12];
  float* out = (float*)d_out;
  char* ws = (char*)d_ws;

  __bf16* kcS    = (__bf16*)(ws + 0);          //  1,048,576 (staging-linear)
  __bf16* vcS    = (__bf16*)(ws + 1048576);    //  1,048,576 (staging-linear)
  __bf16* qbuf   = (__bf16*)(ws + 16777216);   // 16,777,216
  __bf16* klin   = (__bf16*)(ws + 33554432);   //  4,194,304
  __bf16* vlin   = (__bf16*)(ws + 37748736);   //  4,194,304
  __bf16* wfrag  = (__bf16*)(ws + 44040192);   //    196,608
  __bf16* owfrag = (__bf16*)(ws + 44236800);   //    131,072

  k_cvt_w<<<640, 256, 0, stream>>>(qw, kw, vw, ow, wfrag, owfrag);
  k_qkv<<<2048, 256, 0, stream>>>(x, wfrag, qb, kb, vb, qbuf, klin, vlin);
  k_conv<<<1024, 256, 0, stream>>>(klin, vlin, kcw, kcb, vcw, vcb, kcS, vcS);
  k_attn<<<512, 512, 0, stream>>>(qbuf, kcS, vcS, owfrag, ob, out);
}

// Round 25
// 86.245 us; speedup vs baseline: 1.0587x; 1.0587x over previous
//
#include <hip/hip_runtime.h>
#include <hip/hip_bf16.h>

typedef __bf16 v8bf __attribute__((ext_vector_type(8)));
typedef float f32x4 __attribute__((ext_vector_type(4)));
typedef float f32x16 __attribute__((ext_vector_type(16)));
typedef int v2i __attribute__((ext_vector_type(2)));
typedef int v4i __attribute__((ext_vector_type(4)));

#define MFMA16(a, b, c) __builtin_amdgcn_mfma_f32_16x16x32_bf16(a, b, c, 0, 0, 0)
#define MFMA32(a, b, c) __builtin_amdgcn_mfma_f32_32x32x16_bf16(a, b, c, 0, 0, 0)
#define GLOAD16(gp, lp)                                                        \
  __builtin_amdgcn_global_load_lds(                                            \
      (const __attribute__((address_space(1))) void*)(gp),                     \
      (__attribute__((address_space(3))) void*)(lp), 16, 0, 0)

// q scale = SCALE * log2(e) so that exp2(qk) == exp(qk*SCALE)
#define QSCALE 0.18033688011112042f

// ---------------- K0: weights -> MFMA-fragment-ordered bf16 ----------------
__global__ __launch_bounds__(256) void k_cvt_w(const float* __restrict__ qw,
                                               const float* __restrict__ kw,
                                               const float* __restrict__ vw,
                                               const float* __restrict__ ow,
                                               __bf16* __restrict__ wfrag,
                                               __bf16* __restrict__ owfrag) {
  int t = blockIdx.x * 256 + threadIdx.x;  // 640*256 = 163840
  if (t < 98304) {
    int e = t & 7, idx = t >> 3;
    int l = idx & 63; idx >>= 6;
    int n = idx & 3; idx >>= 2;
    int kk = idx & 7, nb = idx >> 3;
    int nn = nb * 64 + n * 16 + (l & 15);
    int k = kk * 32 + 8 * (l >> 4) + e;
    float v;
    if (nn < 256) v = qw[k * 256 + nn] * QSCALE;
    else if (nn < 320) v = kw[k * 64 + (nn - 256)];
    else v = vw[k * 64 + (nn - 320)];
    wfrag[t] = (__bf16)v;
  } else {
    int u = t - 98304;
    int e = u & 7, idx = u >> 3;
    int l = idx & 63; idx >>= 6;
    int n = idx & 3; idx >>= 2;
    int kk = idx & 7, nb = idx >> 3;
    int nn = nb * 64 + n * 16 + (l & 15);
    int k = kk * 32 + 8 * (l >> 4) + e;
    owfrag[u] = (__bf16)ow[k * 256 + nn];
  }
}

// ---------------- K1: fused QKV projection GEMM (R17) ----------------------
__global__ __launch_bounds__(256) void k_qkv(const float* __restrict__ x,
                                             const __bf16* __restrict__ wfrag,
                                             const float* __restrict__ qb,
                                             const float* __restrict__ kb,
                                             const float* __restrict__ vb,
                                             __bf16* __restrict__ qo,
                                             __bf16* __restrict__ klin,
                                             __bf16* __restrict__ vlin) {
  int bx = blockIdx.x;
  int mb = (bx & 7) * 128 + (bx >> 3);  // 1024 % 8 == 0: bijective XCD chunk
  int wave = threadIdx.x >> 6, lane = threadIdx.x & 63;
  int rg = wave >> 1, nh = wave & 1;   // row-group / N-half
  int g = lane >> 4, c = lane & 15;
  int r0 = mb * 32 + rg * 16;
  const v8bf* wf = (const v8bf*)wfrag;

  v8bf a[8];
#pragma unroll
  for (int kk = 0; kk < 8; ++kk) {
    const float* ap = x + (size_t)(r0 + c) * 256 + kk * 32 + 8 * g;
    float4 f0 = *(const float4*)ap;
    float4 f1 = *(const float4*)(ap + 4);
    v8bf t;
    t[0] = (__bf16)f0.x; t[1] = (__bf16)f0.y; t[2] = (__bf16)f0.z; t[3] = (__bf16)f0.w;
    t[4] = (__bf16)f1.x; t[5] = (__bf16)f1.y; t[6] = (__bf16)f1.z; t[7] = (__bf16)f1.w;
    a[kk] = t;
  }
#pragma unroll
  for (int ni = 0; ni < 3; ++ni) {
    int nb = nh * 3 + ni;
    int n0 = nb * 64;
    f32x4 acc[4];
#pragma unroll
    for (int n = 0; n < 4; ++n) acc[n] = f32x4{0.f, 0.f, 0.f, 0.f};
#pragma unroll
    for (int kk = 0; kk < 8; ++kk) {
      v8bf bf[4];
#pragma unroll
      for (int n = 0; n < 4; ++n)
        bf[n] = wf[(((nb * 8 + kk) * 4 + n) << 6) | lane];
#pragma unroll
      for (int n = 0; n < 4; ++n) acc[n] = MFMA16(a[kk], bf[n], acc[n]);
    }
#pragma unroll
    for (int n = 0; n < 4; ++n) {
      int col = n0 + n * 16 + c;
      float bias;
      if (col < 256) bias = qb[col] * QSCALE;
      else if (col < 320) bias = kb[col - 256];
      else bias = vb[col - 320];
#pragma unroll
      for (int j = 0; j < 4; ++j) {
        int row = r0 + 4 * g + j;
        float v = acc[n][j] + bias;
        if (col < 256) qo[(size_t)row * 256 + col] = (__bf16)v;
        else if (col < 320) klin[(size_t)row * 64 + (col - 256)] = (__bf16)v;
        else vlin[(size_t)row * 64 + (col - 320)] = (__bf16)v;
      }
    }
  }
}

// ---------------- K2: depthwise 3x3 stride-2 conv -> staging-linear (R17) --
__global__ __launch_bounds__(256) void k_conv(const __bf16* __restrict__ klin,
                                              const __bf16* __restrict__ vlin,
                                              const float* __restrict__ kw,
                                              const float* __restrict__ kbias,
                                              const float* __restrict__ vw,
                                              const float* __restrict__ vbias,
                                              __bf16* __restrict__ kcS,
                                              __bf16* __restrict__ vcS) {
  int bx = blockIdx.x;
  int phase = bx >> 8;
  int b = (bx >> 5) & 7, tile = bx & 31;  // tile == output row oy
  int u = threadIdx.x;

  if (phase == 0) {
    const __bf16* kin = klin + (size_t)b * 262144;
    int kj = u >> 5, kr = (u & 31) ^ kj;
    float acc[8];
#pragma unroll
    for (int e = 0; e < 8; ++e) acc[e] = kbias[kj * 8 + e];
#pragma unroll
    for (int dy = 0; dy < 3; ++dy) {
      int iy = 2 * tile - 1 + dy;
      if (iy < 0 || iy > 63) continue;
#pragma unroll
      for (int dx = 0; dx < 3; ++dx) {
        int ix = 2 * kr - 1 + dx;
        if (ix < 0 || ix > 63) continue;
        v8bf kv8 = *(const v8bf*)(kin + ((size_t)iy * 64 + ix) * 64 + kj * 8);
        const float* wp = kw + (dy * 3 + dx) * 64 + kj * 8;
#pragma unroll
        for (int e = 0; e < 8; ++e) acc[e] += (float)kv8[e] * wp[e];
      }
    }
    __bf16 o[8];
#pragma unroll
    for (int e = 0; e < 8; ++e) o[e] = (__bf16)acc[e];
    *(v4i*)(kcS + ((size_t)b * 32 + tile) * 2048 + u * 8) = *(v4i*)o;
  } else {
    const __bf16* vin = vlin + (size_t)b * 262144;
    int dt = u >> 7, ks = (u >> 6) & 1, vh = (u >> 5) & 1;
    int cc = (u & 31) ^ (ks * 2 + vh);
    int ch = dt * 32 + cc;
    float vwv[9];
#pragma unroll
    for (int i = 0; i < 9; ++i) vwv[i] = vw[i * 64 + ch];
    float vb0 = vbias[ch];
    __bf16 o[8];
#pragma unroll
    for (int e = 0; e < 8; ++e) {
      int ox = ks * 16 + vh * 8 + e;
      float av = vb0;
#pragma unroll
      for (int dy = 0; dy < 3; ++dy) {
        int iy = 2 * tile - 1 + dy;
        if (iy < 0 || iy > 63) continue;
#pragma unroll
        for (int dx = 0; dx < 3; ++dx) {
          int ix = 2 * ox - 1 + dx;
          if (ix < 0 || ix > 63) continue;
          av += (float)vin[((size_t)iy * 64 + ix) * 64 + ch] * vwv[dy * 3 + dx];
        }
      }
      o[e] = (__bf16)av;
    }
    *(v4i*)(vcS + ((size_t)b * 32 + tile) * 2048 + u * 8) = *(v4i*)o;
  }
}

// ---------------- K3: MQA flash attention + fused out-projection (R19) ----
// grid 512 = 8 b x 64 qtiles; 8 waves (512 thr) = 4 heads x 2 row-groups of
// the same 64 q rows -> ONE K/V staging stream per 64 rows. Race-fixed
// counted-vmcnt 3-buffer pipeline: {vmcnt(1) -> barrier -> GLOAD it+2 ->
// compute}. Each thread stages one 16B chunk per tile.
__global__ __launch_bounds__(512, 4) void k_attn(const __bf16* __restrict__ q,
                                                 const __bf16* __restrict__ kcS,
                                                 const __bf16* __restrict__ vcS,
                                                 const __bf16* __restrict__ owfrag,
                                                 const float* __restrict__ ob,
                                                 float* __restrict__ out) {
  __shared__ __bf16 SMEM[16896];  // 3x4096 KV ring (24KB) / Ot[64][264] union
  int bx = blockIdx.x;
  int L = (bx & 7) * 64 + (bx >> 3);  // 512 % 8 == 0: bijective XCD chunk
  int b = L >> 6, qt = L & 63;
  int tid = threadIdx.x;
  int wave = tid >> 6, lane = tid & 63;
  int h = wave & 3, rg = wave >> 2;    // head / row-group
  int c = lane & 31, hi = lane >> 5;
  size_t rowBase = (size_t)b * 4096 + qt * 64;

  // staging: thread tid stages ONE chunk per tile (K: tid<256, V: tid>=256)
  const __bf16* gsrc = (tid < 256)
                           ? kcS + (size_t)b * 65536 + tid * 8
                           : vcS + (size_t)b * 65536 + (tid - 256) * 8;
  __bf16* ldst = (tid < 256) ? &SMEM[tid * 8] : &SMEM[2048 + (tid - 256) * 8];

  int Koff[4], Voff[2][2];
#pragma unroll
  for (int kk = 0; kk < 4; ++kk) {
    int j = kk * 2 + hi;
    Koff[kk] = (j * 32 + (c ^ j)) * 8;
  }
#pragma unroll
  for (int ks = 0; ks < 2; ++ks)
#pragma unroll
    for (int dt = 0; dt < 2; ++dt) {
      int j = ks * 2 + hi;
      Voff[ks][dt] = (256 + dt * 128 + ks * 64 + hi * 32 + (c ^ j)) * 8;
    }

  const __bf16* qbase = q + (rowBase + rg * 32 + c) * 256 + h * 64 + hi * 8;
  v8bf Qf[4];
#pragma unroll
  for (int kk = 0; kk < 4; ++kk) Qf[kk] = *(const v8bf*)(qbase + kk * 16);

  f32x16 O0 = {}, O1 = {};
  const f32x16 Z16 = {};
  float ls0 = 0.f, ls1 = 0.f, ls2 = 0.f, ls3 = 0.f;

  // prologue: tiles 0 -> buf0, 1 -> buf1 (2 loads in flight per thread)
  GLOAD16(gsrc, ldst);
  GLOAD16(gsrc + 2048, ldst + 4096);

  int cur = 0;  // buffer of tile it; nxt2 = buffer of tile it+2
  int nxt2 = 2;
  for (int it = 0; it < 32; ++it) {
    // own tile-it load landed (only tile it+1's load may be in flight)
    if (it < 31) {
      asm volatile("s_waitcnt vmcnt(1)" ::: "memory");
    } else {
      asm volatile("s_waitcnt vmcnt(0)" ::: "memory");
    }
    __builtin_amdgcn_sched_barrier(0);
    __builtin_amdgcn_s_barrier();
    __builtin_amdgcn_sched_barrier(0);
    // barrier crossed: all waves done with tile it-1's buffer -> safe to
    // overwrite it with tile it+2.
    if (it < 30) {
      GLOAD16(gsrc + (it + 2) * 2048, ldst + nxt2 * 4096);
    }

    const __bf16* base = &SMEM[cur * 4096];
    v8bf Kf[4], Vf[2][2];
#pragma unroll
    for (int kk = 0; kk < 4; ++kk) Kf[kk] = *(const v8bf*)(base + Koff[kk]);
#pragma unroll
    for (int ks = 0; ks < 2; ++ks)
#pragma unroll
      for (int dt = 0; dt < 2; ++dt)
        Vf[ks][dt] = *(const v8bf*)(base + Voff[ks][dt]);

    f32x16 S = MFMA32(Kf[0], Qf[0], Z16);
    S = MFMA32(Kf[1], Qf[1], S);
    S = MFMA32(Kf[2], Qf[2], S);
    S = MFMA32(Kf[3], Qf[3], S);

    // exp2-direct (Q pre-scaled by log2(e)); fp32 tree partial sums
#pragma unroll
    for (int r = 0; r < 16; ++r) S[r] = __builtin_amdgcn_exp2f(S[r]);
    ls0 += (S[0] + S[1]) + (S[2] + S[3]);
    ls1 += (S[4] + S[5]) + (S[6] + S[7]);
    ls2 += (S[8] + S[9]) + (S[10] + S[11]);
    ls3 += (S[12] + S[13]) + (S[14] + S[15]);

    int w[8];
#pragma unroll
    for (int q2 = 0; q2 < 8; ++q2) {
      int r;
      asm("v_cvt_pk_bf16_f32 %0, %1, %2"
          : "=v"(r) : "v"(S[2 * q2]), "v"(S[2 * q2 + 1]));
      w[q2] = r;
    }
    v2i s1 = __builtin_amdgcn_permlane32_swap(w[2], w[0], false, false);
    v2i s2 = __builtin_amdgcn_permlane32_swap(w[3], w[1], false, false);
    v2i s3 = __builtin_amdgcn_permlane32_swap(w[6], w[4], false, false);
    v2i s4 = __builtin_amdgcn_permlane32_swap(w[7], w[5], false, false);
    v4i pa0i, pa1i;
    pa0i[0] = s1[1]; pa0i[1] = s2[1]; pa0i[2] = s1[0]; pa0i[3] = s2[0];
    pa1i[0] = s3[1]; pa1i[1] = s4[1]; pa1i[2] = s3[0]; pa1i[3] = s4[0];
    v8bf pa0 = *(v8bf*)&pa0i, pa1 = *(v8bf*)&pa1i;

    O0 = MFMA32(pa0, Vf[0][0], O0);
    O1 = MFMA32(pa0, Vf[0][1], O1);
    O0 = MFMA32(pa1, Vf[1][0], O0);
    O1 = MFMA32(pa1, Vf[1][1], O1);

    cur = (cur == 2) ? 0 : cur + 1;
    nxt2 = (nxt2 == 2) ? 0 : nxt2 + 1;
  }

  float lsum = (ls0 + ls1) + (ls2 + ls3);
  float tot = lsum + __shfl_xor(lsum, 32);
  float linv = 1.0f / tot;  // lane c holds 1/l for q-row rg*32+c

  __syncthreads();  // all waves done reading KV -> union region free

  // normalized O (bf16, same rounding as before) -> LDS Ot[64][264]
  __bf16(*Ot)[264] = (__bf16(*)[264])SMEM;
#pragma unroll
  for (int r = 0; r < 16; ++r) {
    int qr = (r & 3) + 8 * (r >> 2) + 4 * hi;
    float li = __shfl(linv, qr);
    Ot[rg * 32 + qr][h * 64 + c] = (__bf16)(O0[r] * li);
    Ot[rg * 32 + qr][h * 64 + 32 + c] = (__bf16)(O1[r] * li);
  }
  __syncthreads();

  // out-projection: wave (h, rg) -> out-cols h*64..+63, rows rg*32..+31
  int g = lane >> 4, c16 = lane & 15;
  const v8bf* wf = (const v8bf*)owfrag;
  f32x4 acc[2][4];
#pragma unroll
  for (int m = 0; m < 2; ++m)
#pragma unroll
    for (int n = 0; n < 4; ++n) acc[m][n] = f32x4{0.f, 0.f, 0.f, 0.f};
#pragma unroll
  for (int kk = 0; kk < 8; ++kk) {
    v8bf a0 = *(const v8bf*)&Ot[rg * 32 + c16][kk * 32 + 8 * g];
    v8bf a1 = *(const v8bf*)&Ot[rg * 32 + 16 + c16][kk * 32 + 8 * g];
    v8bf bf[4];
#pragma unroll
    for (int n = 0; n < 4; ++n)
      bf[n] = wf[(((h * 8 + kk) * 4 + n) << 6) | lane];
#pragma unroll
    for (int n = 0; n < 4; ++n) {
      acc[0][n] = MFMA16(a0, bf[n], acc[0][n]);
      acc[1][n] = MFMA16(a1, bf[n], acc[1][n]);
    }
  }
#pragma unroll
  for (int n = 0; n < 4; ++n) {
    int col = h * 64 + n * 16 + c16;
    float bias = ob[col];
#pragma unroll
    for (int m = 0; m < 2; ++m)
#pragma unroll
      for (int j = 0; j < 4; ++j) {
        int row = rg * 32 + m * 16 + 4 * g + j;
        out[(rowBase + row) * 256 + col] = acc[m][n][j] + bias;
      }
  }
}

// ---------------- launcher ----------------
extern "C" void kernel_launch(void* const* d_in, const int* in_sizes, int n_in,
                              void* d_out, int out_size, void* d_ws, size_t ws_size,
                              hipStream_t stream) {
  const float* x   = (const float*)d_in[0];
  const float* qw  = (const float*)d_in[1];
  const float* qb  = (const float*)d_in[2];
  const float* kw  = (const float*)d_in[3];
  const float* kb  = (const float*)d_in[4];
  const float* vw  = (const float*)d_in[5];
  const float* vb  = (const float*)d_in[6];
  const float* kcw = (const float*)d_in[7];
  const float* kcb = (const float*)d_in[8];
  const float* vcw = (const float*)d_in[9];
  const float* vcb = (const float*)d_in[10];
  const float* ow  = (const float*)d_in[11];
  const float* ob  = (const float*)d_in[12];
  float* out = (float*)d_out;
  char* ws = (char*)d_ws;

  __bf16* kcS    = (__bf16*)(ws + 0);          //  1,048,576 (staging-linear)
  __bf16* vcS    = (__bf16*)(ws + 1048576);    //  1,048,576 (staging-linear)
  __bf16* qbuf   = (__bf16*)(ws + 16777216);   // 16,777,216
  __bf16* klin   = (__bf16*)(ws + 33554432);   //  4,194,304
  __bf16* vlin   = (__bf16*)(ws + 37748736);   //  4,194,304
  __bf16* wfrag  = (__bf16*)(ws + 44040192);   //    196,608
  __bf16* owfrag = (__bf16*)(ws + 44236800);   //    131,072

  k_cvt_w<<<640, 256, 0, stream>>>(qw, kw, vw, ow, wfrag, owfrag);
  k_qkv<<<1024, 256, 0, stream>>>(x, wfrag, qb, kb, vb, qbuf, klin, vlin);
  k_conv<<<512, 256, 0, stream>>>(klin, vlin, kcw, kcb, vcw, vcb, kcS, vcS);
  k_attn<<<512, 512, 0, stream>>>(qbuf, kcS, vcS, owfrag, ob, out);
}